// Round 16
// baseline (144.308 us; speedup 1.0000x reference)
//
#include <hip/hip_runtime.h>

// ASG loss, B=128 T=4000 N=64 L=101.
// R16: num ring shrunk 48 -> 32 (+ all stage arrays <= 8) so SROA promotes
//   them to registers. R15 showed launch_bounds does NOT lift VGPR=64: the
//   compiler demotes the 48-float ring to scratch BEFORE regalloc (arrays
//   <=16 promoted fine in R10/R11: VGPR 88/132). Scratch round-trip per
//   step = the ~111 cyc/step floor. Ring[32]&31: load t+32, bperm t+8
//   (24-step ~700cyc cover), exp2 t+4, consume t. Math identical to R14.
// Den/combine/reduce: R15 verbatim. Pure-C bf16 pack (asm pack failed 3/3).

#define TT 4000
#define NN 64
#define LL 101
#define NSEG 64
#define SEGN 62           // counted steps per col (j>=1); col 0: 93
#define SLOTS 93

static constexpr float L2E  = 1.44269504088896340736f;   // log2(e)
static constexpr float LN2F = 0.69314718055994530942f;
static constexpr float NEG2 = -1.0e30f;

// ws layout (floats) ~148 KB
#define WS_X    0                      // [128][64]
#define WS_NF   8192                   // [128][112]
#define WS_HB   22528                  // [128][112]
#define WS_LOSS 36864                  // [128]

#if defined(__has_builtin)
#if __has_builtin(__builtin_amdgcn_mfma_f32_16x16x16bf16_1k)
#define BF16MM 1
#endif
#if __has_builtin(__builtin_amdgcn_exp2f)
#define FEXP2(x) __builtin_amdgcn_exp2f(x)
#endif
#if __has_builtin(__builtin_amdgcn_logf)
#define FLOG2(x) __builtin_amdgcn_logf(x)
#endif
#endif
#ifndef FEXP2
#define FEXP2(x) exp2f(x)
#endif
#ifndef FLOG2
#define FLOG2(x) log2f(x)
#endif

typedef float f32x4 __attribute__((ext_vector_type(4)));
typedef short s16x4 __attribute__((ext_vector_type(4)));
typedef _Float16 h4 __attribute__((ext_vector_type(4)));

// bf16 pack, round-to-nearest-even, pure C (R9/R10/R11/R13/R14/R15-proven)
__device__ __forceinline__ unsigned cvt2(float a, float b) {
#ifdef BF16MM
  const unsigned ua = __builtin_bit_cast(unsigned, a);
  const unsigned ub = __builtin_bit_cast(unsigned, b);
  const unsigned ra = (ua + 0x7FFFu + ((ua >> 16) & 1u)) >> 16;
  const unsigned rb = (ub + 0x7FFFu + ((ub >> 16) & 1u)) >> 16;
  return ra | (rb << 16);
#else
  return __builtin_bit_cast(unsigned,
      __builtin_amdgcn_cvt_pkrtz(fminf(a, 3.0e4f), fminf(b, 3.0e4f)));
#endif
}

__device__ __forceinline__ f32x4 MM(uint2 a, uint2 b, f32x4 c) {
#ifdef BF16MM
  return __builtin_amdgcn_mfma_f32_16x16x16bf16_1k(
      __builtin_bit_cast(s16x4, a), __builtin_bit_cast(s16x4, b), c, 0, 0, 0);
#else
  return __builtin_amdgcn_mfma_f32_16x16x16f16(
      __builtin_bit_cast(h4, a), __builtin_bit_cast(h4, b), c, 0, 0, 0);
#endif
}

// DPP lane shift: 0x138 = wave_shr:1, 0x130 = wave_shl:1 (boundary reads 0).
template<int CTRL>
__device__ __forceinline__ float dppf(float x) {
  return __builtin_bit_cast(float, __builtin_amdgcn_update_dpp(
      0, __builtin_bit_cast(int, x), CTRL, 0xf, 0xf, true));
}

// ======================= denominator kernel ================================
__global__ __launch_bounds__(128, 1) void asg_den(
    const float* __restrict__ E, const float* __restrict__ TR,
    float* __restrict__ ws)
{
  const int bid  = blockIdx.x;
  const int w    = threadIdx.x >> 6;
  const int lane = threadIdx.x & 63;
  const int b    = bid >> 1;
  const int p    = bid & 1;
  const int g4   = p * 2 + w;              // segment group 0..3
  const float* em = E + (size_t)b * TT * NN;

  const int c = lane & 15, g = lane >> 4;
  const int j = g4 * 16 + c;               // segment 0..63

  uint2 Af[4][4];
#pragma unroll
  for (int rt = 0; rt < 4; ++rt)
#pragma unroll
    for (int kt = 0; kt < 4; ++kt) {
      const float* tr = TR + (size_t)(16 * rt + c + 1) * NN + 16 * kt + 4 * g;
      Af[rt][kt].x = cvt2(FEXP2(tr[0] * L2E), FEXP2(tr[1] * L2E));
      Af[rt][kt].y = cvt2(FEXP2(tr[2] * L2E), FEXP2(tr[3] * L2E));
    }

  f32x4 P[4];
#pragma unroll
  for (int rt = 0; rt < 4; ++rt)
#pragma unroll
    for (int e = 0; e < 4; ++e) {
      const int row = 16 * rt + 4 * g + e;
      P[rt][e] = (j == 0) ? FEXP2((em[row] + TR[row]) * L2E) : 1.0f;
    }

  float Csum = 0.f, snap = 0.f;
  const float* ebase = em + (size_t)(SEGN * j + 1) * NN + 4 * g;

#define COLSUM(dst) { float t_ =                                               \
    (P[0].x + P[0].y + P[0].z + P[0].w) + (P[1].x + P[1].y + P[1].z + P[1].w)  \
  + (P[2].x + P[2].y + P[2].z + P[2].w) + (P[3].x + P[3].y + P[3].z + P[3].w); \
  t_ += __shfl_xor(t_, 16); t_ += __shfl_xor(t_, 32);                          \
  (dst) = fmaxf(t_, 1e-30f); }

#define RENORM() { float cs_; COLSUM(cs_);                                     \
  const int mb_ = ((__builtin_bit_cast(int, cs_) >> 23) & 255) - 127;          \
  const float sc_ = __builtin_bit_cast(float, (127 - mb_) << 23);              \
  P[0] *= sc_; P[1] *= sc_; P[2] *= sc_; P[3] *= sc_;                          \
  Csum += (float)mb_; }

#define ELOAD(D, s_) { const int se_ = (s_) < (SLOTS - 1) ? (s_) : (SLOTS - 1);\
  const f32x4* p_ = (const f32x4*)(ebase + (size_t)se_ * NN);                  \
  D[0] = p_[0]; D[1] = p_[4]; D[2] = p_[8]; D[3] = p_[12]; }

#define STEP(M)                                                                \
  {                                                                            \
    uint2 Bf[4];                                                               \
    _Pragma("unroll") for (int kt = 0; kt < 4; ++kt) {                         \
      Bf[kt].x = cvt2(P[kt].x, P[kt].y);                                       \
      Bf[kt].y = cvt2(P[kt].z, P[kt].w);                                       \
    }                                                                          \
    _Pragma("unroll") for (int rt = 0; rt < 4; ++rt) {                         \
      f32x4 acc = {0.f, 0.f, 0.f, 0.f};                                        \
      acc = MM(Af[rt][0], Bf[0], acc);                                         \
      acc = MM(Af[rt][1], Bf[1], acc);                                         \
      acc = MM(Af[rt][2], Bf[2], acc);                                         \
      acc = MM(Af[rt][3], Bf[3], acc);                                         \
      _Pragma("unroll") for (int e = 0; e < 4; ++e)                            \
        P[rt][e] = fminf(fmaxf(                                                \
            acc[e] * FEXP2(fmaf(M[rt][e], L2E, -6.7f)), 1e-20f), 1e25f);       \
    }                                                                          \
  }

#define SUB(Ebuf, ss, kr)                                                      \
  { f32x4 T_[4] = {Ebuf[0], Ebuf[1], Ebuf[2], Ebuf[3]};                        \
    ELOAD(Ebuf, (ss) + 6);                                                     \
    STEP(T_);                                                                  \
    if ((ss) == 30) { float cs2_; COLSUM(cs2_);                                \
                      snap = Csum + FLOG2(cs2_) + 6.7f * 31.f; }               \
    if ((kr) == 5) RENORM(); }

  f32x4 E0[4], E1[4], E2[4], E3[4], E4[4], E5[4];
  ELOAD(E0, 0); ELOAD(E1, 1); ELOAD(E2, 2);
  ELOAD(E3, 3); ELOAD(E4, 4); ELOAD(E5, 5);

  for (int it = 0; it < 15; ++it) {        // steps s = 0..89
    const int s = 6 * it;
    SUB(E0, s, 0);     SUB(E1, s + 1, 1); SUB(E2, s + 2, 2);
    SUB(E3, s + 3, 3); SUB(E4, s + 4, 4); SUB(E5, s + 5, 5);
  }
  // tail s = 90, 91, 92
  { f32x4 T_[4] = {E0[0], E0[1], E0[2], E0[3]}; STEP(T_); }
  { f32x4 T_[4] = {E1[0], E1[1], E1[2], E1[3]}; STEP(T_); }
  { f32x4 T_[4] = {E2[0], E2[1], E2[2], E2[3]}; STEP(T_); }

  float csf; COLSUM(csf);
  const float fin = Csum + FLOG2(csf) + 6.7f * (float)SLOTS;
  const float X = fin - ((j == 0) ? 0.f : snap);
  if (lane < 16) ws[WS_X + b * NSEG + g4 * 16 + lane] = X;

#undef SUB
#undef STEP
#undef ELOAD
#undef RENORM
#undef COLSUM
}

// ======================= numerator kernel ==================================
template<int DIR>
__device__ __forceinline__ void num_chain(const float* __restrict__ em,
                                          const float* __restrict__ TR,
                                          const int* __restrict__ Y,
                                          float* __restrict__ ws,
                                          const int b, const int l)
{
  const bool v0 = (2 * l     <= 100);
  const bool v1 = (2 * l + 1 <= 100);
  const int k0 = v0 ? 2 * l     : 100;
  const int k1 = v1 ? 2 * l + 1 : 100;
  const int y0 = Y[b * LL + k0];
  const int y1 = Y[b * LL + k1];
  const float SW0 = v0 ? FEXP2(TR[(y0 + 1) * NN + y0] * L2E) : 0.f;
  const float SW1 = v1 ? FEXP2(TR[(y1 + 1) * NN + y1] * L2E) : 0.f;
  float WLOC, WRECV, B0, B1, C;
  bool recvok;
  if (DIR == 0) {
    WLOC = v1 ? FEXP2(TR[(y1 + 1) * NN + y0] * L2E) : 0.f;
    const int ym0 = Y[b * LL + (k0 > 0 ? k0 - 1 : 0)];
    recvok = v0 && (l > 0);
    WRECV = recvok ? FEXP2(TR[(y0 + 1) * NN + ym0] * L2E) : 0.f;
    B0 = (l == 0) ? 1.f : 0.f;
    B1 = 0.f;
    C  = (l == 0) ? (TR[y0] + em[y0]) * L2E : 0.f;
  } else {
    WLOC = v1 ? FEXP2(TR[(y1 + 1) * NN + y0] * L2E) : 0.f;
    const int kp = (2 * l + 2 <= 100) ? 2 * l + 2 : 100;
    const int yp1 = Y[b * LL + kp];
    recvok = (2 * l + 2 <= 100);
    WRECV = recvok ? FEXP2(TR[(yp1 + 1) * NN + y1] * L2E) : 0.f;
    B0 = (l == 50) ? 1.f : 0.f;
    B1 = 0.f;
    C  = (l == 50) ? em[(size_t)(TT - 1) * NN + y0] * L2E : 0.f;
  }

#define TROW(t) ((size_t)((DIR == 0) ? (t) : (TT - 1 - (t))) * NN)
#define RADDR(t) em[TROW(((t) < 1999 ? (t) : 1999)) + l]

  float ring[32];                      // ring[t & 31] = row t (lane = col)
  float SH0[8], SH1[8];                // bpermuted raw values, index t & 7
  float PE0[8], PE1[8];                // exp2'd pairs, index t & 7
  float ADJ = 0.f;

#define RESCALE()                                                              \
  {                                                                            \
    const float v_ = B0 + B1;                                                  \
    const int bits_ = __builtin_bit_cast(int, v_);                             \
    const int m_ = (v_ > 0.f) ? ((bits_ >> 23) & 255) - 127 : 0;               \
    const float sc_ = __builtin_bit_cast(float, (127 - m_) << 23);             \
    B0 *= sc_; B1 *= sc_; C += (float)m_;                                      \
    const float Cn_ = dppf<(DIR == 0) ? 0x138 : 0x130>(C);                     \
    const float dC_ = fminf(fmaxf(Cn_ - C, -120.f), 120.f);                    \
    ADJ = recvok ? FEXP2(dC_) * WRECV : 0.f;                                   \
  }

#define NSTEP2(E0v, E1v)                                                       \
  {                                                                            \
    if (DIR == 0) {                                                            \
      const float NB = dppf<0x138>(B1);                                        \
      const float t0 = fmaf(NB, ADJ, B0 * SW0);                                \
      const float t1 = fmaf(B0, WLOC, B1 * SW1);                               \
      B0 = t0 * (E0v); B1 = t1 * (E1v);                                        \
    } else {                                                                   \
      const float NB = dppf<0x130>(B0);                                        \
      const float t1 = fmaf(NB, ADJ, B1 * SW1);                                \
      const float t0 = fmaf(B1, WLOC, B0 * SW0);                               \
      B0 = t0 * (E0v); B1 = t1 * (E1v);                                        \
    }                                                                          \
  }

  // prologue: issue rows 1..32; bpermute t = 1..8; exp2 t = 1..4
#pragma unroll
  for (int k = 1; k <= 32; ++k) ring[k & 31] = RADDR(k);
#pragma unroll
  for (int t = 1; t <= 8; ++t) {
    const float r_ = ring[t & 31];
    SH0[t & 7] = __shfl(r_, y0);
    SH1[t & 7] = __shfl(r_, y1);
  }
#pragma unroll
  for (int t = 1; t <= 4; ++t) {
    PE0[t & 7] = FEXP2(SH0[t & 7] * L2E);
    PE1[t & 7] = FEXP2(SH1[t & 7] * L2E);
  }

  // one step at static phase k (t = tc + k, tc === 1 mod 32):
  //  consume PE[t]; bpermute ring -> SH for t+8; exp2 SH -> PE for t+4;
  //  load row t+32 into ring slot t&31.
#define QSTEP(k)                                                               \
  { if (((k) & 7) == 0) RESCALE();                                             \
    NSTEP2(PE0[(1 + (k)) & 7], PE1[(1 + (k)) & 7]);                            \
    { const float r_ = ring[(1 + (k) + 8) & 31];                               \
      SH0[(1 + (k) + 8) & 7] = __shfl(r_, y0);                                 \
      SH1[(1 + (k) + 8) & 7] = __shfl(r_, y1); }                               \
    PE0[(1 + (k) + 4) & 7] = FEXP2(SH0[(1 + (k) + 4) & 7] * L2E);              \
    PE1[(1 + (k) + 4) & 7] = FEXP2(SH1[(1 + (k) + 4) & 7] * L2E);              \
    ring[(1 + (k)) & 31] = RADDR(tc + (k) + 32); }

#define Q4(k0)  QSTEP(k0) QSTEP((k0) + 1) QSTEP((k0) + 2) QSTEP((k0) + 3)
#define Q16(k0) Q4(k0) Q4((k0) + 4) Q4((k0) + 8) Q4((k0) + 12)

  for (int i = 0; i < 62; ++i) {           // t = 1 .. 1984
    const int tc = 1 + 32 * i;
    Q16(0) Q16(16)
  }
  {                                        // tail t = 1985 .. 1999 (15 steps)
    const int tc = 1985;
    Q4(0) Q4(4)
    Q4(8)
    QSTEP(12) QSTEP(13) QSTEP(14)
  }

#undef Q16
#undef Q4
#undef QSTEP
#undef NSTEP2
#undef RESCALE
#undef RADDR
#undef TROW

  const float o0 = (B0 > 1e-37f) ? C + FLOG2(B0) : NEG2;
  const float o1 = (B1 > 1e-37f) ? C + FLOG2(B1) : NEG2;
  const int base = (DIR ? WS_HB : WS_NF) + b * 112;
  if (v0) ws[base + 2 * l]     = o0;
  if (v1) ws[base + 2 * l + 1] = o1;
}

__global__ __launch_bounds__(64, 1) void asg_num(
    const float* __restrict__ E, const float* __restrict__ TR,
    const int* __restrict__ Y, float* __restrict__ ws)
{
  const int bid = blockIdx.x;
  const int b   = bid >> 1;
  const int dir = bid & 1;
  const float* em = E + (size_t)b * TT * NN;
  if (dir == 0) num_chain<0>(em, TR, Y, ws, b, (int)threadIdx.x);
  else          num_chain<1>(em, TR, Y, ws, b, (int)threadIdx.x);
}

// ======================= combine / reduce ==================================
__global__ __launch_bounds__(128) void asg_combine(
    const float* __restrict__ TR, const int* __restrict__ Y,
    const float* __restrict__ ws, float* __restrict__ lossv)
{
  const int b = blockIdx.x;
  const int tid = threadIdx.x;
  __shared__ float sN[LL], sH[LL], red[128];
  __shared__ float sLogZ;

  if (tid == 0) {
    float z = 0.f;
    for (int s = 0; s < NSEG; ++s) z += ws[WS_X + b * NSEG + s];
    sLogZ = z;                              // log2 Z
  }
  if (tid < LL) { sN[tid] = ws[WS_NF + b * 112 + tid]; sH[tid] = ws[WS_HB + b * 112 + tid]; }
  __syncthreads();

  float val2 = -3.0e38f;
  if (tid < LL) {
    const int l = tid;
    const int y = Y[b * LL + l];
    const float s1 = sN[l] + TR[(y + 1) * NN + y] * L2E;
    float s2 = NEG2;
    if (l > 0) {
      const int ymm = Y[b * LL + l - 1];
      s2 = sN[l - 1] + TR[(y + 1) * NN + ymm] * L2E;
    }
    const float m = fmaxf(s1, s2);
    val2 = m + log2f(exp2f(s1 - m) + exp2f(s2 - m)) + sH[l];
  }
  red[tid] = val2;
  __syncthreads();
  if (tid == 0) {
    float m = red[0];
    for (int k = 1; k < LL; ++k) m = fmaxf(m, red[k]);
    float s = 0.f;
    for (int k = 0; k < LL; ++k) s += exp2f(red[k] - m);
    const float tgt2 = m + log2f(s);
    lossv[b] = (sLogZ - tgt2) * LN2F / (float)LL;
  }
}

__global__ __launch_bounds__(64) void asg_reduce(const float* __restrict__ lossv,
                                                 float* __restrict__ out)
{
  const int tid = threadIdx.x;
  float v = lossv[tid] + lossv[tid + 64];
  for (int off = 32; off; off >>= 1) v += __shfl_xor(v, off);
  if (tid == 0) out[0] = v * (1.0f / 128.0f);
}

extern "C" void kernel_launch(void* const* d_in, const int* in_sizes, int n_in,
                              void* d_out, int out_size, void* d_ws, size_t ws_size,
                              hipStream_t stream) {
  const float* E  = (const float*)d_in[0];
  const float* TR = (const float*)d_in[1];
  const int*   Y  = (const int*)d_in[2];
  float* out = (float*)d_out;
  float* ws  = (float*)d_ws;
  float* lossv = ws + WS_LOSS;

  asg_den<<<dim3(256), dim3(128), 0, stream>>>(E, TR, ws);
  asg_num<<<dim3(256), dim3(64), 0, stream>>>(E, TR, Y, ws);
  asg_combine<<<dim3(128), dim3(128), 0, stream>>>(TR, Y, ws, lossv);
  asg_reduce<<<dim3(1), dim3(64), 0, stream>>>(lossv, out);
}

// Round 17
// 127.913 us; speedup vs baseline: 1.1282x; 1.1282x over previous
//
#include <hip/hip_runtime.h>

// ASG loss, B=128 T=4000 N=64 L=101.
// R17: array-free numerator. R13-R16 pinned asg_num at ~92us because hipcc
//   demotes ring-indexed local arrays to scratch (VGPR 44-64 across 4
//   variants; arrays<=16 promoted at VGPR 88-132 in R10/R11). Fix: NO
//   arrays - three 32-float NAMED-SCALAR banks; and NO bpermute - y0/y1
//   are lane-constant so gather em[row+y] directly (row = one 256B line
//   group shared by all lanes). 16-step bodies; issue bank m+2 while
//   consuming bank m (32-47 step load->use distance, covers HBM).
// Fused: blocks 0..255 den (R13/R16-verified verbatim), 256..383 num
//   (wave0=fwd, wave1=bwd) so den and num overlap.
// Pure-C bf16 pack (v_cvt_pk asm failed 3/3 this session).

#define TT 4000
#define NN 64
#define LL 101
#define NSEG 64
#define SEGN 62           // counted steps per col (j>=1); col 0: 93
#define SLOTS 93

static constexpr float L2E  = 1.44269504088896340736f;   // log2(e)
static constexpr float LN2F = 0.69314718055994530942f;
static constexpr float NEG2 = -1.0e30f;

// ws layout (floats) ~148 KB
#define WS_X    0                      // [128][64]
#define WS_NF   8192                   // [128][112]
#define WS_HB   22528                  // [128][112]
#define WS_LOSS 36864                  // [128]

#if defined(__has_builtin)
#if __has_builtin(__builtin_amdgcn_mfma_f32_16x16x16bf16_1k)
#define BF16MM 1
#endif
#if __has_builtin(__builtin_amdgcn_exp2f)
#define FEXP2(x) __builtin_amdgcn_exp2f(x)
#endif
#if __has_builtin(__builtin_amdgcn_logf)
#define FLOG2(x) __builtin_amdgcn_logf(x)
#endif
#endif
#ifndef FEXP2
#define FEXP2(x) exp2f(x)
#endif
#ifndef FLOG2
#define FLOG2(x) log2f(x)
#endif

typedef float f32x4 __attribute__((ext_vector_type(4)));
typedef short s16x4 __attribute__((ext_vector_type(4)));
typedef _Float16 h4 __attribute__((ext_vector_type(4)));

// bf16 pack, round-to-nearest-even, pure C
__device__ __forceinline__ unsigned cvt2(float a, float b) {
#ifdef BF16MM
  const unsigned ua = __builtin_bit_cast(unsigned, a);
  const unsigned ub = __builtin_bit_cast(unsigned, b);
  const unsigned ra = (ua + 0x7FFFu + ((ua >> 16) & 1u)) >> 16;
  const unsigned rb = (ub + 0x7FFFu + ((ub >> 16) & 1u)) >> 16;
  return ra | (rb << 16);
#else
  return __builtin_bit_cast(unsigned,
      __builtin_amdgcn_cvt_pkrtz(fminf(a, 3.0e4f), fminf(b, 3.0e4f)));
#endif
}

__device__ __forceinline__ f32x4 MM(uint2 a, uint2 b, f32x4 c) {
#ifdef BF16MM
  return __builtin_amdgcn_mfma_f32_16x16x16bf16_1k(
      __builtin_bit_cast(s16x4, a), __builtin_bit_cast(s16x4, b), c, 0, 0, 0);
#else
  return __builtin_amdgcn_mfma_f32_16x16x16f16(
      __builtin_bit_cast(h4, a), __builtin_bit_cast(h4, b), c, 0, 0, 0);
#endif
}

// DPP lane shift: 0x138 = wave_shr:1, 0x130 = wave_shl:1 (boundary reads 0).
template<int CTRL>
__device__ __forceinline__ float dppf(float x) {
  return __builtin_bit_cast(float, __builtin_amdgcn_update_dpp(
      0, __builtin_bit_cast(int, x), CTRL, 0xf, 0xf, true));
}

// ======================= numerator chain (array-free) ======================
template<int DIR>
__device__ __forceinline__ void num_chain(const float* __restrict__ em,
                                          const float* __restrict__ TR,
                                          const int* __restrict__ Y,
                                          float* __restrict__ ws,
                                          const int b, const int l)
{
  const bool v0 = (2 * l     <= 100);
  const bool v1 = (2 * l + 1 <= 100);
  const int k0 = v0 ? 2 * l     : 100;
  const int k1 = v1 ? 2 * l + 1 : 100;
  const int y0 = Y[b * LL + k0];
  const int y1 = Y[b * LL + k1];
  const float SW0 = v0 ? FEXP2(TR[(y0 + 1) * NN + y0] * L2E) : 0.f;
  const float SW1 = v1 ? FEXP2(TR[(y1 + 1) * NN + y1] * L2E) : 0.f;
  float WLOC, WRECV, B0, B1, C;
  bool recvok;
  if (DIR == 0) {
    WLOC = v1 ? FEXP2(TR[(y1 + 1) * NN + y0] * L2E) : 0.f;
    const int ym0 = Y[b * LL + (k0 > 0 ? k0 - 1 : 0)];
    recvok = v0 && (l > 0);
    WRECV = recvok ? FEXP2(TR[(y0 + 1) * NN + ym0] * L2E) : 0.f;
    B0 = (l == 0) ? 1.f : 0.f;
    B1 = 0.f;
    C  = (l == 0) ? (TR[y0] + em[y0]) * L2E : 0.f;
  } else {
    WLOC = v1 ? FEXP2(TR[(y1 + 1) * NN + y0] * L2E) : 0.f;
    const int kp = (2 * l + 2 <= 100) ? 2 * l + 2 : 100;
    const int yp1 = Y[b * LL + kp];
    recvok = (2 * l + 2 <= 100);
    WRECV = recvok ? FEXP2(TR[(yp1 + 1) * NN + y1] * L2E) : 0.f;
    B0 = (l == 50) ? 1.f : 0.f;
    B1 = 0.f;
    C  = (l == 50) ? em[(size_t)(TT - 1) * NN + y0] * L2E : 0.f;
  }

  constexpr int ST = (DIR == 0) ? NN : -NN;       // row stride in floats
#define TROW0(t) ((long)((DIR == 0) ? (t) : (TT - 1 - (t))) * NN)

  float ADJ = 0.f;

#define RESCALE()                                                              \
  {                                                                            \
    const float v_ = B0 + B1;                                                  \
    const int bits_ = __builtin_bit_cast(int, v_);                             \
    const int m_ = (v_ > 0.f) ? ((bits_ >> 23) & 255) - 127 : 0;               \
    const float sc_ = __builtin_bit_cast(float, (127 - m_) << 23);             \
    B0 *= sc_; B1 *= sc_; C += (float)m_;                                      \
    const float Cn_ = dppf<(DIR == 0) ? 0x138 : 0x130>(C);                     \
    const float dC_ = fminf(fmaxf(Cn_ - C, -120.f), 120.f);                    \
    ADJ = recvok ? FEXP2(dC_) * WRECV : 0.f;                                   \
  }

#define NSTEP2(E0v, E1v)                                                       \
  {                                                                            \
    if (DIR == 0) {                                                            \
      const float NB = dppf<0x138>(B1);                                        \
      const float t0 = fmaf(NB, ADJ, B0 * SW0);                                \
      const float t1 = fmaf(B0, WLOC, B1 * SW1);                               \
      B0 = t0 * (E0v); B1 = t1 * (E1v);                                        \
    } else {                                                                   \
      const float NB = dppf<0x130>(B0);                                        \
      const float t1 = fmaf(NB, ADJ, B1 * SW1);                                \
      const float t0 = fmaf(B1, WLOC, B0 * SW0);                               \
      B0 = t0 * (E0v); B1 = t1 * (E1v);                                        \
    }                                                                          \
  }

  // named-scalar banks: Bk##k##a / Bk##k##b = (em[t][y0], em[t][y1]) at
  // t = bank_start + k.  No arrays anywhere -> nothing for SROA to demote.
#define NB_DECL(Bk)                                                            \
  float Bk##0a, Bk##0b, Bk##1a, Bk##1b, Bk##2a, Bk##2b, Bk##3a, Bk##3b,        \
        Bk##4a, Bk##4b, Bk##5a, Bk##5b, Bk##6a, Bk##6b, Bk##7a, Bk##7b,        \
        Bk##8a, Bk##8b, Bk##9a, Bk##9b, Bk##10a, Bk##10b, Bk##11a, Bk##11b,    \
        Bk##12a, Bk##12b, Bk##13a, Bk##13b, Bk##14a, Bk##14b, Bk##15a, Bk##15b;

  NB_DECL(KA) NB_DECL(KB) NB_DECL(KC)

#define NLD(Bk, k)                                                             \
  Bk##k##a = p0_[(k) * ST];                                                    \
  Bk##k##b = p1_[(k) * ST];

#define NISSUE(Bk, ts)                                                         \
  { const float* p0_ = em + TROW0(ts) + y0;                                    \
    const float* p1_ = em + TROW0(ts) + y1;                                    \
    NLD(Bk,0)  NLD(Bk,1)  NLD(Bk,2)  NLD(Bk,3)                                 \
    NLD(Bk,4)  NLD(Bk,5)  NLD(Bk,6)  NLD(Bk,7)                                 \
    NLD(Bk,8)  NLD(Bk,9)  NLD(Bk,10) NLD(Bk,11)                                \
    NLD(Bk,12) NLD(Bk,13) NLD(Bk,14) NLD(Bk,15) }

#define NRUN1(Bk, k)                                                           \
  { const float E0_ = FEXP2(Bk##k##a * L2E);                                   \
    const float E1_ = FEXP2(Bk##k##b * L2E);                                   \
    NSTEP2(E0_, E1_); }

#define NRUN8A(Bk) RESCALE();                                                  \
  NRUN1(Bk,0) NRUN1(Bk,1) NRUN1(Bk,2) NRUN1(Bk,3)                              \
  NRUN1(Bk,4) NRUN1(Bk,5) NRUN1(Bk,6) NRUN1(Bk,7)
#define NRUN8B(Bk) RESCALE();                                                  \
  NRUN1(Bk,8)  NRUN1(Bk,9)  NRUN1(Bk,10) NRUN1(Bk,11)                          \
  NRUN1(Bk,12) NRUN1(Bk,13) NRUN1(Bk,14) NRUN1(Bk,15)
#define NRUN16(Bk) NRUN8A(Bk) NRUN8B(Bk)

  // prologue: banks for t=1..16 and t=17..32
  NISSUE(KA, 1)
  NISSUE(KB, 17)

  // 41 iterations x 3 bodies x 16 steps = t 1..1968
  for (int i = 0; i < 41; ++i) {
    const int tc = 1 + 48 * i;
    NISSUE(KC, tc + 32)  NRUN16(KA)        // consume t=tc..tc+15
    NISSUE(KA, tc + 48)  NRUN16(KB)        // consume t=tc+16..tc+31
    NISSUE(KB, tc + 64)  NRUN16(KC)        // consume t=tc+32..tc+47
  }
  // KA holds t=1969..1984 ; KB holds t=1985..2000 (t=2000 load is in-bounds
  // of the 4000-row batch for both DIRs, value unused)
  NRUN16(KA)                               // t=1969..1984
  NRUN8A(KB)                               // t=1985..1992
  RESCALE();                               // t=1993 (g=1992, %8==0)
  NRUN1(KB,8) NRUN1(KB,9) NRUN1(KB,10) NRUN1(KB,11)
  NRUN1(KB,12) NRUN1(KB,13) NRUN1(KB,14)   // t=1993..1999

#undef NRUN16
#undef NRUN8B
#undef NRUN8A
#undef NRUN1
#undef NISSUE
#undef NLD
#undef NB_DECL
#undef NSTEP2
#undef RESCALE
#undef TROW0

  const float o0 = (B0 > 1e-37f) ? C + FLOG2(B0) : NEG2;
  const float o1 = (B1 > 1e-37f) ? C + FLOG2(B1) : NEG2;
  const int base = (DIR ? WS_HB : WS_NF) + b * 112;
  if (v0) ws[base + 2 * l]     = o0;
  if (v1) ws[base + 2 * l + 1] = o1;
}

// ======================= fused main kernel =================================
__global__ __launch_bounds__(128, 1) void asg_main(
    const float* __restrict__ E, const float* __restrict__ TR,
    const int* __restrict__ Y, float* __restrict__ ws)
{
  const int bid  = blockIdx.x;
  const int w    = threadIdx.x >> 6;
  const int lane = threadIdx.x & 63;

  if (bid < 256) {
    // ================= denominator (R13/R16 verbatim) ====================
    const int b    = bid >> 1;
    const int p    = bid & 1;
    const int g4   = p * 2 + w;            // segment group 0..3
    const float* em = E + (size_t)b * TT * NN;

    const int c = lane & 15, g = lane >> 4;
    const int j = g4 * 16 + c;             // segment 0..63

    uint2 Af[4][4];
#pragma unroll
    for (int rt = 0; rt < 4; ++rt)
#pragma unroll
      for (int kt = 0; kt < 4; ++kt) {
        const float* tr = TR + (size_t)(16 * rt + c + 1) * NN + 16 * kt + 4 * g;
        Af[rt][kt].x = cvt2(FEXP2(tr[0] * L2E), FEXP2(tr[1] * L2E));
        Af[rt][kt].y = cvt2(FEXP2(tr[2] * L2E), FEXP2(tr[3] * L2E));
      }

    f32x4 P[4];
#pragma unroll
    for (int rt = 0; rt < 4; ++rt)
#pragma unroll
      for (int e = 0; e < 4; ++e) {
        const int row = 16 * rt + 4 * g + e;
        P[rt][e] = (j == 0) ? FEXP2((em[row] + TR[row]) * L2E) : 1.0f;
      }

    float Csum = 0.f, snap = 0.f;
    const float* ebase = em + (size_t)(SEGN * j + 1) * NN + 4 * g;

#define COLSUM(dst) { float t_ =                                               \
    (P[0].x + P[0].y + P[0].z + P[0].w) + (P[1].x + P[1].y + P[1].z + P[1].w)  \
  + (P[2].x + P[2].y + P[2].z + P[2].w) + (P[3].x + P[3].y + P[3].z + P[3].w); \
  t_ += __shfl_xor(t_, 16); t_ += __shfl_xor(t_, 32);                          \
  (dst) = fmaxf(t_, 1e-30f); }

#define RENORM() { float cs_; COLSUM(cs_);                                     \
  const int mb_ = ((__builtin_bit_cast(int, cs_) >> 23) & 255) - 127;          \
  const float sc_ = __builtin_bit_cast(float, (127 - mb_) << 23);              \
  P[0] *= sc_; P[1] *= sc_; P[2] *= sc_; P[3] *= sc_;                          \
  Csum += (float)mb_; }

#define ELOAD(D, s_) { const int se_ = (s_) < (SLOTS - 1) ? (s_) : (SLOTS - 1);\
  const f32x4* p_ = (const f32x4*)(ebase + (size_t)se_ * NN);                  \
  D[0] = p_[0]; D[1] = p_[4]; D[2] = p_[8]; D[3] = p_[12]; }

#define STEP(M)                                                                \
  {                                                                            \
    uint2 Bf[4];                                                               \
    _Pragma("unroll") for (int kt = 0; kt < 4; ++kt) {                         \
      Bf[kt].x = cvt2(P[kt].x, P[kt].y);                                       \
      Bf[kt].y = cvt2(P[kt].z, P[kt].w);                                       \
    }                                                                          \
    _Pragma("unroll") for (int rt = 0; rt < 4; ++rt) {                         \
      f32x4 acc = {0.f, 0.f, 0.f, 0.f};                                        \
      acc = MM(Af[rt][0], Bf[0], acc);                                         \
      acc = MM(Af[rt][1], Bf[1], acc);                                         \
      acc = MM(Af[rt][2], Bf[2], acc);                                         \
      acc = MM(Af[rt][3], Bf[3], acc);                                         \
      _Pragma("unroll") for (int e = 0; e < 4; ++e)                            \
        P[rt][e] = fminf(fmaxf(                                                \
            acc[e] * FEXP2(fmaf(M[rt][e], L2E, -6.7f)), 1e-20f), 1e25f);       \
    }                                                                          \
  }

#define SUB(Ebuf, ss, kr)                                                      \
  { f32x4 T_[4] = {Ebuf[0], Ebuf[1], Ebuf[2], Ebuf[3]};                        \
    ELOAD(Ebuf, (ss) + 6);                                                     \
    STEP(T_);                                                                  \
    if ((ss) == 30) { float cs2_; COLSUM(cs2_);                                \
                      snap = Csum + FLOG2(cs2_) + 6.7f * 31.f; }               \
    if ((kr) == 5) RENORM(); }

    f32x4 E0[4], E1[4], E2[4], E3[4], E4[4], E5[4];
    ELOAD(E0, 0); ELOAD(E1, 1); ELOAD(E2, 2);
    ELOAD(E3, 3); ELOAD(E4, 4); ELOAD(E5, 5);

    for (int it = 0; it < 15; ++it) {      // steps s = 0..89
      const int s = 6 * it;
      SUB(E0, s, 0);     SUB(E1, s + 1, 1); SUB(E2, s + 2, 2);
      SUB(E3, s + 3, 3); SUB(E4, s + 4, 4); SUB(E5, s + 5, 5);
    }
    // tail s = 90, 91, 92
    { f32x4 T_[4] = {E0[0], E0[1], E0[2], E0[3]}; STEP(T_); }
    { f32x4 T_[4] = {E1[0], E1[1], E1[2], E1[3]}; STEP(T_); }
    { f32x4 T_[4] = {E2[0], E2[1], E2[2], E2[3]}; STEP(T_); }

    float csf; COLSUM(csf);
    const float fin = Csum + FLOG2(csf) + 6.7f * (float)SLOTS;
    const float X = fin - ((j == 0) ? 0.f : snap);
    if (lane < 16) ws[WS_X + b * NSEG + g4 * 16 + lane] = X;

#undef SUB
#undef STEP
#undef ELOAD
#undef RENORM
#undef COLSUM

  } else {
    // ================= numerator: wave0 fwd, wave1 bwd ===================
    const int b = bid - 256;
    const float* em = E + (size_t)b * TT * NN;
    if (w == 0) num_chain<0>(em, TR, Y, ws, b, lane);
    else        num_chain<1>(em, TR, Y, ws, b, lane);
  }
}

// ======================= combine / reduce ==================================
__global__ __launch_bounds__(128) void asg_combine(
    const float* __restrict__ TR, const int* __restrict__ Y,
    const float* __restrict__ ws, float* __restrict__ lossv)
{
  const int b = blockIdx.x;
  const int tid = threadIdx.x;
  __shared__ float sN[LL], sH[LL], red[128];
  __shared__ float sLogZ;

  if (tid == 0) {
    float z = 0.f;
    for (int s = 0; s < NSEG; ++s) z += ws[WS_X + b * NSEG + s];
    sLogZ = z;                              // log2 Z
  }
  if (tid < LL) { sN[tid] = ws[WS_NF + b * 112 + tid]; sH[tid] = ws[WS_HB + b * 112 + tid]; }
  __syncthreads();

  float val2 = -3.0e38f;
  if (tid < LL) {
    const int l = tid;
    const int y = Y[b * LL + l];
    const float s1 = sN[l] + TR[(y + 1) * NN + y] * L2E;
    float s2 = NEG2;
    if (l > 0) {
      const int ymm = Y[b * LL + l - 1];
      s2 = sN[l - 1] + TR[(y + 1) * NN + ymm] * L2E;
    }
    const float m = fmaxf(s1, s2);
    val2 = m + log2f(exp2f(s1 - m) + exp2f(s2 - m)) + sH[l];
  }
  red[tid] = val2;
  __syncthreads();
  if (tid == 0) {
    float m = red[0];
    for (int k = 1; k < LL; ++k) m = fmaxf(m, red[k]);
    float s = 0.f;
    for (int k = 0; k < LL; ++k) s += exp2f(red[k] - m);
    const float tgt2 = m + log2f(s);
    lossv[b] = (sLogZ - tgt2) * LN2F / (float)LL;
  }
}

__global__ __launch_bounds__(64) void asg_reduce(const float* __restrict__ lossv,
                                                 float* __restrict__ out)
{
  const int tid = threadIdx.x;
  float v = lossv[tid] + lossv[tid + 64];
  for (int off = 32; off; off >>= 1) v += __shfl_xor(v, off);
  if (tid == 0) out[0] = v * (1.0f / 128.0f);
}

extern "C" void kernel_launch(void* const* d_in, const int* in_sizes, int n_in,
                              void* d_out, int out_size, void* d_ws, size_t ws_size,
                              hipStream_t stream) {
  const float* E  = (const float*)d_in[0];
  const float* TR = (const float*)d_in[1];
  const int*   Y  = (const int*)d_in[2];
  float* out = (float*)d_out;
  float* ws  = (float*)d_ws;
  float* lossv = ws + WS_LOSS;

  // 384 blocks: 0..255 den (2 waves each), 256..383 num (fwd+bwd waves).
  asg_main<<<dim3(384), dim3(128), 0, stream>>>(E, TR, Y, ws);
  asg_combine<<<dim3(128), dim3(128), 0, stream>>>(TR, Y, ws, lossv);
  asg_reduce<<<dim3(1), dim3(64), 0, stream>>>(lossv, out);
}